// Round 9
// baseline (242.416 us; speedup 1.0000x reference)
//
#include <hip/hip_runtime.h>
#include <hip/hip_fp16.h>

// B=32768, D_IN=256, H1=256, D_OUT=64, E=32, T=16
#define NTHR 512
#define BM   128
#define NBLK 256
#define NEXP 32

using f16x8 = __attribute__((ext_vector_type(8))) _Float16;
using f16x4 = __attribute__((ext_vector_type(4))) _Float16;
using f32x4 = __attribute__((ext_vector_type(4))) float;
using u32x4 = __attribute__((ext_vector_type(4))) unsigned int;
using u32x2 = __attribute__((ext_vector_type(2))) unsigned int;

// ---- per-expert stream (bytes): stride 182272 ----
//   [0)      8 x 16KB W1 fragment tiles (kc 0..7)
//   [131072) 24KB WVplus wn0 frags
//   [155648) 24KB WVplus wn1 frags   (together: one contiguous 48KB M-stage)
//   [180224) 1KB b1 (256 f32)
//   [181248) 1KB b2v (80 f32 used)
static constexpr size_t ESTRIDE_B = 182272;   // = 91136 halves

__device__ __forceinline__ unsigned short f2h(float x){
  _Float16 h = (_Float16)x; return __builtin_bit_cast(unsigned short, h);
}

typedef __attribute__((address_space(3))) void lds_void;
typedef const __attribute__((address_space(1))) void glb_void;
__device__ __forceinline__ void gll16(const void* g, void* l){
  __builtin_amdgcn_global_load_lds((glb_void*)g, (lds_void*)l, 16, 0, 0);
}

#define VMW(N)  asm volatile("s_waitcnt vmcnt(" #N ")" ::: "memory")
#define LGKM0   asm volatile("s_waitcnt lgkmcnt(0)" ::: "memory")
#define SB      __builtin_amdgcn_sched_barrier(0)
#define BARRIER do { SB; __builtin_amdgcn_s_barrier(); SB; } while(0)

// ---------------------------------------------------------------------------
// prep 1: W1 [E][256][256] f32 -> per-(e,kc) 16KB fragment tile.
// frag(ct,l,j) = W1[e][kc*32 + (l>>4)*8 + j][ct*16 + (l&15)]
// ---------------------------------------------------------------------------
__global__ __launch_bounds__(256) void prep_w1frag(const float* __restrict__ W1,
                                                   unsigned short* __restrict__ strm){
  const int e = blockIdx.x >> 3, kc = blockIdx.x & 7;
  const float* se = W1 + (size_t)e*65536 + (size_t)kc*32*256;
  unsigned short* de = strm + (size_t)e*91136 + kc*8192;
  for (int fl = threadIdx.x; fl < 1024; fl += 256){
    const int ct = fl >> 6, l = fl & 63;
    const float* s0 = se + (size_t)((l>>4)*8)*256 + ct*16 + (l&15);
    union { unsigned short s[8]; u32x4 v; } h8;
    #pragma unroll
    for (int j = 0; j < 8; j++) h8.s[j] = f2h(s0[(size_t)j*256]);
    *reinterpret_cast<u32x4*>(&de[fl*8]) = h8.v;
  }
}

// ---------------------------------------------------------------------------
// prep 2: WVplus = [ W2@V (64 cols) | fp16-hi of W2@kt (16) | fp16-residual (16) ]
// fragment-pair layout for 16x16x16 B-op. Also b1, b2v into stream.
// grid: 256 blocks = (e, oct of 32 k2-rows)
// ---------------------------------------------------------------------------
__global__ __launch_bounds__(256) void prep_wvp(
    const float* __restrict__ W2, const float* __restrict__ V,
    const float* __restrict__ Km, const float* __restrict__ Q,
    const float* __restrict__ b1, const float* __restrict__ b2,
    unsigned short* __restrict__ strm, float* __restrict__ out)
{
  const int e = blockIdx.x >> 3, oct = blockIdx.x & 7;
  const int t = threadIdx.x;
  __shared__ float lv[64*64];     // V[e]
  __shared__ float ktlT[64*16];   // kt transposed: [i][t]
  __shared__ float lw2[32*64];    // W2 rows oct*32..+31

  for (int i = t; i < 1024; i += 256)
    *reinterpret_cast<float4*>(&lv[i*4]) = *reinterpret_cast<const float4*>(V + (size_t)e*4096 + i*4);
  for (int i = t; i < 512; i += 256)
    *reinterpret_cast<float4*>(&lw2[i*4]) = *reinterpret_cast<const float4*>(W2 + (size_t)e*16384 + (size_t)oct*2048 + i*4);
  #pragma unroll
  for (int pass = 0; pass < 4; pass++){
    const int id = t + pass*256;
    const int tt = id >> 6, i = id & 63;
    const float4* Kr = reinterpret_cast<const float4*>(Km + (size_t)(e*64 + i)*64);
    const float4* qr = reinterpret_cast<const float4*>(Q + tt*64);
    float s = 0.f;
    #pragma unroll
    for (int j = 0; j < 16; j++){ float4 a = Kr[j], b = qr[j]; s += a.x*b.x+a.y*b.y+a.z*b.z+a.w*b.w; }
    ktlT[i*16 + tt] = s;
  }
  __syncthreads();

  const int k2 = oct*32 + (t >> 3);
  const int cb = t & 7;
  const int c0 = cb*12;
  const float* w2r = &lw2[(t>>3)*64];
  const float* gp[3]; int gs[3]; bool gv[3];
  #pragma unroll
  for (int q = 0; q < 3; q++){
    const int cg = c0 + q*4;
    gv[q] = (cg < 80);
    if (cg < 64){ gp[q] = &lv[cg];        gs[q] = 64; }
    else        { gp[q] = &ktlT[cg - 64]; gs[q] = 16; }
  }
  float pv[12];
  #pragma unroll
  for (int n = 0; n < 12; n++) pv[n] = 0.f;
  for (int i = 0; i < 64; i++){
    const float w = w2r[i];
    #pragma unroll
    for (int q = 0; q < 3; q++){
      if (gv[q]){
        const float4 vq = *reinterpret_cast<const float4*>(gp[q] + i*gs[q]);
        pv[q*4+0] += w*vq.x; pv[q*4+1] += w*vq.y; pv[q*4+2] += w*vq.z; pv[q*4+3] += w*vq.w;
      }
    }
  }
  const int wn_ = k2 >> 7, fn = (k2 >> 4) & 7, fnp = fn >> 1, half = fn & 1;
  const int g2 = (k2 >> 2) & 3, jj = k2 & 3;
  unsigned short* fb = strm + (size_t)e*91136 + (wn_ ? 77824 : 65536);
  #pragma unroll
  for (int n = 0; n < 12; n++){
    const int cc = c0 + n;
    if (cc < 64){
      const int ct = cc >> 4, lc = cc & 15, l = g2*16 + lc;
      fb[(fnp*6+ct)*512 + l*8 + half*4 + jj] = f2h(pv[n]);
    } else if (cc < 80){
      const int lc = cc - 64, l = g2*16 + lc;
      const float s = pv[n];
      const unsigned short hi = f2h(s);
      const float rem = s - (float)__builtin_bit_cast(_Float16, hi);
      fb[(fnp*6+4)*512 + l*8 + half*4 + jj] = hi;
      fb[(fnp*6+5)*512 + l*8 + half*4 + jj] = f2h(rem);
    }
  }
  if (oct == 0){
    float* b1d = reinterpret_cast<float*>((char*)strm + (size_t)e*ESTRIDE_B + 180224);
    b1d[t] = b1[e*256 + t];
  }
  if (oct == 1 && t < 80){
    float s = 0.f;
    if (t < 64){ for (int i = 0; i < 64; i++) s += b2[e*64+i]*lv[i*64+t]; }
    else       { for (int i = 0; i < 64; i++) s += b2[e*64+i]*ktlT[i*16 + (t-64)]; }
    float* bd = reinterpret_cast<float*>((char*)strm + (size_t)e*ESTRIDE_B + 181248);
    bd[t] = s;
  }
  if (blockIdx.x == 0 && t == 0) out[2097152] = -10.24032768f;
}

// ---------------------------------------------------------------------------
// main kernel: 256 blocks x 512 thr, 1 block/CU.
// LDS (148 KB): 3 x 48KB slots (2 rotating W1, slot2 fixed = M-buf/exch)
//               + 2 x 2KB aux.  5 barriers/expert (P0,P1,P2,M,X).
// GEMM1 in 3 fat phases (3+3+2 kc); softmax finalize for expert e-1 is
// DEFERRED into P0(e), overlapping its ds_read burst. Both split-K halves
// flow through exch (scores f32, pv fp16) so p0/p1 die at X (no reg growth).
// Counted vmcnt (FIFO-simulated): P0=8, P1=2, P2=6, M=6.
// ---------------------------------------------------------------------------
__global__ __launch_bounds__(NTHR, 2) __attribute__((amdgpu_waves_per_eu(2, 2)))
void moe_main(const float* __restrict__ X, const int* __restrict__ task,
              const unsigned short* __restrict__ strm, float* __restrict__ out)
{
  __shared__ unsigned short smem[75776];   // 151,552 B
  unsigned char* exch = (unsigned char*)smem + 98304;   // slot2 (aliases M-buf)

  const int tid  = threadIdx.x;
  const int lane = tid & 63;
  const int wid  = tid >> 6;
  const int g    = lane >> 4;
  const int c    = lane & 15;
  const int wm   = wid >> 1, wn = wid & 1;   // 4x2 grid: 32 rows x 128 cols
  const int row0 = blockIdx.x * BM;

  auto issue48 = [&](const unsigned short* src, int sloth){  // 48KB, 6 vm-ops/wave
    #pragma unroll
    for (int q = 0; q < 6; q++)
      gll16(src + q*4096 + tid*8, &smem[sloth + q*4096 + tid*8]);
  };
  auto issue32 = [&](const unsigned short* src, int sloth){  // 32KB, 4 vm-ops/wave
    #pragma unroll
    for (int q = 0; q < 4; q++)
      gll16(src + q*4096 + tid*8, &smem[sloth + q*4096 + tid*8]);
  };
  auto issueAux = [&](const unsigned short* es_, int k){     // 2KB, 2 vm-ops/wave
    gll16(es_ + 90112 + lane*8, &smem[73728 + k*1024 + lane*8]);
    gll16(es_ + 90624 + lane*8, &smem[73728 + k*1024 + 512 + lane*8]);
  };

  // ---- persistent X A-frags + tasks (FIFO-drained before ring ops) ----
  f16x8 af[2][8];
  #pragma unroll
  for (int fm = 0; fm < 2; fm++){
    const float* xr = X + (size_t)(row0 + wm*32 + fm*16 + c)*256;
    #pragma unroll
    for (int kc = 0; kc < 8; kc++){
      const f32x4 v0 = *reinterpret_cast<const f32x4*>(xr + kc*32 + g*8);
      const f32x4 v1 = *reinterpret_cast<const f32x4*>(xr + kc*32 + g*8 + 4);
      union { unsigned short s[8]; f16x8 h; } h8;
      #pragma unroll
      for (int j = 0; j < 4; j++){ h8.s[j] = f2h(v0[j]); h8.s[4+j] = f2h(v1[j]); }
      af[fm][kc] = h8.h;
    }
  }
  const int4 tq = *reinterpret_cast<const int4*>(&task[row0 + wm*32 + wn*16 + g*4]);
  const int tsk4[4] = {tq.x, tq.y, tq.z, tq.w};

  VMW(0);   // ring FIFO below contains ONLY ring ops

  // prologue (order matches steady pre-P0 FIFO: A6, B6, aux2)
  issue48(strm,          0);        // A(e0): kc0-2 -> slot0
  issue48(strm + 24576,  24576);    // B(e0): kc3-5 -> slot1
  issueAux(strm, 0);

  f32x4 oacc[4];
  float m_[4], d_[4];
  #pragma unroll
  for (int j = 0; j < 4; j++){
    m_[j] = -1e30f; d_[j] = 0.f;
    #pragma unroll
    for (int ct = 0; ct < 4; ct++) oacc[ct][j] = 0.f;
  }

// one kc-tile: 8 b128 reads + 16 MFMA
#define G1STEP(BASEH, KC) do { \
    f16x8 bfr_[8]; \
    _Pragma("unroll") \
    for (int fnl = 0; fnl < 8; fnl++) \
      bfr_[fnl] = *reinterpret_cast<const f16x8*>(&smem[(BASEH) + (wn*8+fnl)*512 + lane*8]); \
    __builtin_amdgcn_s_setprio(1); \
    _Pragma("unroll") \
    for (int fnl = 0; fnl < 8; fnl++){ \
      acc1[fnl][0] = __builtin_amdgcn_mfma_f32_16x16x32_f16(bfr_[fnl], af[0][KC], acc1[fnl][0], 0,0,0); \
      acc1[fnl][1] = __builtin_amdgcn_mfma_f32_16x16x32_f16(bfr_[fnl], af[1][KC], acc1[fnl][1], 0,0,0); \
    } \
    __builtin_amdgcn_s_setprio(0); \
  } while(0)

// GEMM2 step into named p0/p1 (rule #20: static indices only)
#define MSTEP(FNP) do { \
    u32x4 pr[6]; \
    _Pragma("unroll") \
    for (int i = 0; i < 6; i++) \
      pr[i] = *reinterpret_cast<const u32x4*>(&smem[49152 + wn*12288 + ((FNP)*6+i)*512 + lane*8]); \
    const f32x4 b1a = *reinterpret_cast<const f32x4*>(b1f + wn*128 + (2*(FNP)+0)*16 + g*4); \
    const f32x4 b1b = *reinterpret_cast<const f32x4*>(b1f + wn*128 + (2*(FNP)+1)*16 + g*4); \
    __builtin_amdgcn_s_setprio(1); \
    _Pragma("unroll") \
    for (int half = 0; half < 2; half++){ \
      const int fnl = (FNP)*2 + half; \
      const f32x4 bb = half ? b1b : b1a; \
      f16x4 a0, a1; \
      _Pragma("unroll") \
      for (int j = 0; j < 4; j++){ \
        a0[j] = (_Float16)fmaxf(acc1[fnl][0][j] + bb[j], 0.f); \
        a1[j] = (_Float16)fmaxf(acc1[fnl][1][j] + bb[j], 0.f); \
      } \
      _Pragma("unroll") \
      for (int ct = 0; ct < 6; ct++){ \
        union { u32x4 v; struct { f16x4 lo, hi; } h; } u; u.v = pr[ct]; \
        const f16x4 bfr = half ? u.h.hi : u.h.lo; \
        const int ci = (ct < 5) ? ct : 4; \
        p0[ci] = __builtin_amdgcn_mfma_f32_16x16x16f16(a0, bfr, p0[ci], 0,0,0); \
        p1[ci] = __builtin_amdgcn_mfma_f32_16x16x16f16(a1, bfr, p1[ci], 0,0,0); \
      } \
    } \
    __builtin_amdgcn_s_setprio(0); \
  } while(0)

// write one acc half (pv as fp16, scores as f32) to its exch sub-region
#define XW(ACC, EB) do { \
    _Pragma("unroll") \
    for (int ct = 0; ct < 4; ct++){ \
      union { unsigned short s[4]; u32x2 v; } p_; \
      _Pragma("unroll") \
      for (int j = 0; j < 4; j++) p_.s[j] = f2h(ACC[ct][j]); \
      *reinterpret_cast<u32x2*>((EB) + ct*512 + lane*8) = p_.v; \
    } \
    *reinterpret_cast<f32x4*>((EB) + 2048 + lane*16) = ACC[4]; \
  } while(0)

// deferred finalize: sum self+partner halves from exch, softmax-update
#define XFIN(B2F) do { \
    const unsigned char* ebS = exch + (wm*2 + wn)*6144 + wn*3072; \
    const unsigned char* ebP = exch + (wm*2 + (wn^1))*6144 + wn*3072; \
    float b2c[4]; \
    _Pragma("unroll") \
    for (int ct = 0; ct < 4; ct++) b2c[ct] = (B2F)[ct*16 + c]; \
    const float b2s = (B2F)[64 + c]; \
    f32x4 pvv[4]; \
    _Pragma("unroll") \
    for (int ct = 0; ct < 4; ct++){ \
      union { u32x2 v; unsigned short s[4]; } pa_, pb_; \
      pa_.v = *reinterpret_cast<const u32x2*>(ebS + ct*512 + lane*8); \
      pb_.v = *reinterpret_cast<const u32x2*>(ebP + ct*512 + lane*8); \
      _Pragma("unroll") \
      for (int j = 0; j < 4; j++) \
        pvv[ct][j] = (float)__builtin_bit_cast(_Float16, pa_.s[j]) \
                   + (float)__builtin_bit_cast(_Float16, pb_.s[j]) + b2c[ct]; \
    } \
    const f32x4 s1 = *reinterpret_cast<const f32x4*>(ebS + 2048 + lane*16); \
    const f32x4 s2 = *reinterpret_cast<const f32x4*>(ebP + 2048 + lane*16); \
    _Pragma("unroll") \
    for (int j = 0; j < 4; j++){ \
      const float sv = s1[j] + s2[j] + b2s; \
      const float s  = __shfl(sv, (lane & 48) | tsk4[j]); \
      const float mn = fmaxf(m_[j], s); \
      const float al = __expf(m_[j] - mn); \
      const float p  = __expf(s - mn); \
      d_[j] = d_[j]*al + p; \
      m_[j] = mn; \
      _Pragma("unroll") \
      for (int ct = 0; ct < 4; ct++) \
        oacc[ct][j] = oacc[ct][j]*al + p*pvv[ct][j]; \
    } \
  } while(0)

  for (int e = 0; e < NEXP; e++){
    const unsigned short* es  = strm + (size_t)e*91136;
    const unsigned short* esn = (e == NEXP-1) ? strm : es + 91136;  // wrap: static counts
    const int pA = (e & 1) * 24576;          // this expert's A/C slot (half-offset)
    const int pB = 24576 - pA;               // this expert's B slot
    const float* b1f = reinterpret_cast<const float*>(&smem[73728 + (e & 1)*1024]);
    f32x4 acc1[8][2] = {};

    // ---- P0: kc0,1,2 from slotA; deferred finalize of e-1 overlaps ----
    VMW(8); BARRIER;
    if (e > 0){
      const float* b2p = reinterpret_cast<const float*>(&smem[73728 + ((e+1) & 1)*1024]) + 256;
      XFIN(b2p);
    }
    G1STEP(pA,          0);
    G1STEP(pA +  8192,  1);
    G1STEP(pA + 16384,  2);

    // ---- P1: kc3,4,5 from slotB; issue C (kc6,7 -> slotA), D (M-buf -> slot2) ----
    VMW(2); BARRIER;
    issue32(es + 49152, pA);                 // C_e
    issue48(es + 65536, 49152);              // D_e (WVplus 48KB)
    G1STEP(pB,          3);
    G1STEP(pB +  8192,  4);
    G1STEP(pB + 16384,  5);

    // ---- P2: kc6,7 from slotA; issue next-A (kc0-2 of e+1 -> slotB) ----
    VMW(6); BARRIER;
    issue48(esn, pB);                        // A_{e+1}
    G1STEP(pA,          6);
    G1STEP(pA +  8192,  7);

    // ---- M: GEMM2 (pv + scores) from acc1; issue next-B (kc3-5 -> slotA) ----
    VMW(6); BARRIER;
    issue48(esn + 24576, pA);                // B_{e+1}
    f32x4 p0[5] = {}, p1[5] = {};
    MSTEP(0); MSTEP(1); MSTEP(2); MSTEP(3);

    // ---- X: write BOTH halves to exch (slot2, M reads done); issue aux ----
    BARRIER;
    {
      unsigned char* eb = exch + wid*6144;
      XW(p0, eb);
      XW(p1, eb + 3072);
    }
    issueAux(esn, (e+1) & 1);
    LGKM0;                                    // exch writes visible at next barrier
  }

  // ---- tail: finalize expert 31 ----
  BARRIER;
  {
    const float* b2p = reinterpret_cast<const float*>(&smem[73728 + (31 & 1)*1024]) + 256;
    XFIN(b2p);
  }
#undef XFIN
#undef XW
#undef MSTEP
#undef G1STEP

  // ---- output: rows wm*32 + wn*16 + g*4 + j ----
  #pragma unroll
  for (int j = 0; j < 4; j++){
    const float inv = 1.f / d_[j];
    float* orow = out + (size_t)(row0 + wm*32 + wn*16 + g*4 + j)*64;
    #pragma unroll
    for (int ct = 0; ct < 4; ct++)
      orow[ct*16 + c] = oacc[ct][j]*inv;
  }
}

// ---------------------------------------------------------------------------
extern "C" void kernel_launch(void* const* d_in, const int* in_sizes, int n_in,
                              void* d_out, int out_size, void* d_ws, size_t ws_size,
                              hipStream_t hs)
{
  (void)in_sizes; (void)n_in; (void)out_size; (void)ws_size;
  const float* X   = (const float*)d_in[0];
  const int*   tsk = (const int*)  d_in[1];
  const float* W1  = (const float*)d_in[2];
  const float* b1  = (const float*)d_in[3];
  const float* W2  = (const float*)d_in[4];
  const float* b2  = (const float*)d_in[5];
  const float* Q   = (const float*)d_in[6];
  const float* Km  = (const float*)d_in[7];
  const float* Vm  = (const float*)d_in[8];
  float* out = (float*)d_out;

  unsigned short* strm = (unsigned short*)d_ws;

  prep_w1frag<<<dim3(256), dim3(256), 0, hs>>>(W1, strm);
  prep_wvp  <<<dim3(256), dim3(256), 0, hs>>>(W2, Vm, Km, Q, b1, b2, strm, out);
  moe_main  <<<dim3(NBLK), dim3(NTHR), 0, hs>>>(X, tsk, strm, out);
}